// Round 9
// baseline (265.419 us; speedup 1.0000x reference)
//
#include <hip/hip_runtime.h>
#include <math.h>

// ---------------------------------------------------------------------------
// TemporalGCN: 2-layer LSTM (per-node sequences) -> 2 GCN rounds -> edge MLP.
//
// R17: R16 post-mortem: lstm phase = 13.7K cyc with DS 8.2K and VALU 5.9K
// nearly SERIAL (8.2+5.9 = 14.1 ~ 13.7 measured) -- barrier-lockstep: all
// waves burst ds_reads together (VALU idle), then FMA together (DS idle).
// Two low-risk, separately-attributable changes:
//   1. k_lstm_fused: #pragma unroll 2 -> 4 on both gate seq-loops. Gives
//      the scheduler 4 independent dot-chains to interleave seq s+1's
//      ds_read_b128 under seq s's FMA tail (compiler emits fine-grained
//      lgkmcnt(N) - m97 evidence). Target: phase -> max(DS,VALU)+barrier
//      ~9-10K cyc -> lstm ~65-72us. Spill tripwire: FETCH/WRITE must stay
//      ~1.16/0.4MB, VGPR <= ~130.
//   2. k_mlp: batch the 128 dependent uu/vt loads 16-at-a-time (8 k per
//      chunk into temps; FP order identical) -> 16 outstanding VMEM loads
//      cover L2 latency instead of load->use serial.
// Everything else verbatim R16 (proven clean: VGPR 116, no spill, 80us).
//
// Bit-exactness: unrolling does not reorder any per-seq accumulation chain;
// k_mlp batching only hoists loads (acc = uvv[q]+vvv[q], then ascending-q
// e5 adds, unchanged). absmax 0.0 preserved.
// ---------------------------------------------------------------------------

#define Hd   64
#define Ed   5
#define Fd   6
#define Bd   8
#define Wd   12
#define Nd   200
#define NSEQ (Bd*Nd)        // 1600 sequences (b,n)
#define NG   (4*Hd)         // 256 gate rows
#define SEQPB 8             // sequences per fused-LSTM block (200 % 8 == 0)
#define WP   (Wd + 1)       // padded t-columns in x_sh (col 12 = zeros)
#define LNEPS 1e-5f

__device__ __forceinline__ float sigm(float x) { return 1.0f / (1.0f + __expf(-x)); }
__device__ __forceinline__ float tanh_fast(float x) {
  float ax = fabsf(x);
  float t  = __expf(-2.0f * ax);
  float r  = (1.0f - t) / (1.0f + t);
  return copysignf(r, x);
}

// --------------------------------------------------------------------------
// Prep: gcnWT[round][k][u]; epWT[round][e][u]; W1aT[k][n]=W1[n][k];
// W1bT[k][n]=W1[n][64+k]. Sizes: 8192 + 640 + 4096 + 4096 = 17024 elements.
__global__ __launch_bounds__(256) void k_prep(
    const float* __restrict__ gcn_W, const float* __restrict__ ep_W,
    const float* __restrict__ W1,
    float* __restrict__ gcnWT, float* __restrict__ epWT,
    float* __restrict__ W1aT, float* __restrict__ W1bT)
{
  int idx = blockIdx.x * 256 + threadIdx.x;
  if (idx < 8192) {                        // gcnWT[r][k][u] = gcn_W[r][u][k]
    int round = idx >> 12, rem = idx & 4095;
    int k = rem >> 6, u = rem & 63;
    gcnWT[idx] = gcn_W[round * 4096 + u * 64 + k];
  } else if (idx < 8832) {                 // epWT[r][e][u] = ep_W[r][u][e]
    int r0 = idx - 8192;
    int round = r0 / 320, rem = r0 % 320;
    int e = rem >> 6, u = rem & 63;
    epWT[r0] = ep_W[round * 320 + u * Ed + e];
  } else if (idx < 12928) {                // W1aT[k][n] = W1[n][k]
    int r0 = idx - 8832;
    int k = r0 >> 6, n = r0 & 63;
    W1aT[r0] = W1[n * 133 + k];
  } else if (idx < 17024) {                // W1bT[k][n] = W1[n][64+k]
    int r0 = idx - 12928;
    int k = r0 >> 6, n = r0 & 63;
    W1bT[r0] = W1[n * 133 + 64 + k];
  }
}

// --------------------------------------------------------------------------
// Fused 2-layer LSTM. 200 blocks x 512 threads, 8 seqs/block.
// Phase t in [0,13]:
//   A waves (tid<256): fused body for t<=12 -- L0 gate dot (stored iff
//     t<12) + xproj off the SAME h0_sh b128 stream (stored iff t>=1).
//   B waves: L1 gates step t-2 (t>=2), a0 seeded from x1_sh[(t-1)&1].
// barrier; L0 update (A, t<12), L1 update (B, t>=2); barrier.
__global__ __launch_bounds__(512) void k_lstm_fused(
    const float* __restrict__ nf,                       // (B,W,N,F)
    const float* __restrict__ Wih0, const float* __restrict__ Whh0,
    const float* __restrict__ bih0, const float* __restrict__ bhh0,
    const float* __restrict__ Wih1, const float* __restrict__ Whh1,
    const float* __restrict__ bih1, const float* __restrict__ bhh1,
    float* __restrict__ hout)                           // (NSEQ, H)
{
  __shared__ float x_sh[SEQPB][WP * Fd];   // 624 (col 12 zeroed)
  __shared__ float wx_sh[NG * Fd];         // 1536: Wih0 rows (row-major)
  __shared__ float h0_sh[SEQPB][Hd];       // 512
  __shared__ float h1_sh[SEQPB][Hd];       // 512
  __shared__ float g0_sh[SEQPB][NG];       // 2048 (post-activation gates L0)
  __shared__ float g1_sh[SEQPB][NG];       // 2048 (post-activation gates L1)
  __shared__ float x1_sh[2][SEQPB][NG];    // 4096 (xv = Wih1.h0 + bias1)

  const int tid  = threadIdx.x;
  const int seq0 = blockIdx.x * SEQPB;
  const int b    = seq0 / Nd;              // uniform (200 % 8 == 0)
  const int n0   = seq0 % Nd;

  for (int idx = tid; idx < SEQPB * WP * Fd; idx += 512) {
    int s = idx / (WP * Fd), r = idx - s * (WP * Fd);
    int t = r / Fd, f = r - t * Fd;
    x_sh[s][r] = (t < Wd) ? nf[((b * Wd + t) * Nd + (n0 + s)) * Fd + f] : 0.f;
  }
  for (int idx = tid; idx < NG * Fd; idx += 512)
    wx_sh[idx] = Wih0[idx];                // linear copy (row-major match)
  ((float*)h0_sh)[tid] = 0.f;              // 512 floats, one per thread
  ((float*)h1_sh)[tid] = 0.f;

  const bool isA = (tid < 256);
  const int j  = tid & 255;                // gate row within this layer
  const int jt = j >> 6;                   // 0=i,1=f,2=g,3=o (wave-uniform)
  const int u  = tid & 63;
  const int w  = (tid >> 6) & 3;           // update ownership: seqs {w, w+4}

  // Per-thread weights: A = Whh0[j] + Wih1[j] (128 wf; Wih0 row via LDS);
  // B = Whh1[j] (64 wf). Plain launch_bounds -> AGPR-backed overflow OK.
  float4 wh[16];                           // Whh0 row j (A) / Whh1 row j (B)
  float4 wi1[16];                          // Wih1 row j (A only)
  float  bias0 = 0.f, bias1 = 0.f;
  if (isA) {
    const float4* wr = (const float4*)(Whh0 + j * Hd);
    #pragma unroll
    for (int q = 0; q < 16; ++q) wh[q] = wr[q];
    const float4* xr = (const float4*)(Wih1 + j * Hd);
    #pragma unroll
    for (int q = 0; q < 16; ++q) wi1[q] = xr[q];
    bias0 = bih0[j] + bhh0[j];
    bias1 = bih1[j] + bhh1[j];
  } else {
    const float4* wr = (const float4*)(Whh1 + j * Hd);
    #pragma unroll
    for (int q = 0; q < 16; ++q) wh[q] = wr[q];
  }

  float cA = 0.f, cB = 0.f;                // cell states for seqs w, w+4
  float hA = 0.f, hB = 0.f;                // B threads: final h1 for w, w+4
  const float* wxp = wx_sh + j * Fd;       // A's Wih0 row (LDS, 2-way = free)
  __syncthreads();

  for (int t = 0; t <= Wd + 1; ++t) {
    // ================= gate section ======================================
    if (isA) {
      if (t <= Wd) {                       // single fused body for t in [0,12]
        #pragma unroll 4
        for (int s = 0; s < SEQPB; ++s) {
          const float* xp = &x_sh[s][t * Fd];        // col 12 = zeros
          float a0 = bias0, a1 = 0.f, a2 = 0.f, a3 = 0.f;
          #pragma unroll
          for (int f = 0; f < Fd; ++f) a1 += xp[f] * wxp[f];
          float xacc = 0.f;
          const float4* h4 = (const float4*)h0_sh[s];
          #pragma unroll
          for (int q = 0; q < 16; ++q) {
            float4 hv = h4[q];                       // ONE b128, two dots
            float d = hv.x * wh[q].x + hv.y * wh[q].y + hv.z * wh[q].z + hv.w * wh[q].w;
            if ((q & 3) == 0) a0 += d; else if ((q & 3) == 1) a1 += d;
            else if ((q & 3) == 2) a2 += d; else a3 += d;
            xacc = fmaf(hv.x, wi1[q].x, xacc);       // xproj for L1 step t-1
            xacc = fmaf(hv.y, wi1[q].y, xacc);
            xacc = fmaf(hv.z, wi1[q].z, xacc);
            xacc = fmaf(hv.w, wi1[q].w, xacc);
          }
          float acc = (a0 + a1) + (a2 + a3);
          if (t < Wd)  g0_sh[s][j] = (jt == 2) ? tanh_fast(acc) : sigm(acc);
          if (t >= 1)  x1_sh[t & 1][s][j] = xacc + bias1;
        }
      }
    } else {
      if (t >= 2) {                        // L1 gates step t-2
        #pragma unroll 4
        for (int s = 0; s < SEQPB; ++s) {
          float a0 = x1_sh[(t - 1) & 1][s][j];   // xv(t-2), written phase t-1
          float a1 = 0.f, a2 = 0.f, a3 = 0.f;
          const float4* h4 = (const float4*)h1_sh[s];
          #pragma unroll
          for (int q = 0; q < 16; ++q) {
            float4 hv = h4[q];
            float d = hv.x * wh[q].x + hv.y * wh[q].y + hv.z * wh[q].z + hv.w * wh[q].w;
            if ((q & 3) == 0) a0 += d; else if ((q & 3) == 1) a1 += d;
            else if ((q & 3) == 2) a2 += d; else a3 += d;
          }
          float acc = (a0 + a1) + (a2 + a3);
          g1_sh[s][j] = (jt == 2) ? tanh_fast(acc) : sigm(acc);
        }
      }
    }
    __syncthreads();                       // gates/xv ready; all h reads done

    // ================= update section (verbatim R9 ownership) ============
    if (isA) {
      if (t < Wd) {                        // L0 update step t
        const float* gb = g0_sh[w];
        float iv = gb[u], fv = gb[64 + u], gv = gb[128 + u], ov = gb[192 + u];
        cA = fv * cA + iv * gv;
        hA = ov * tanh_fast(cA);
        h0_sh[w][u] = hA;
        const float* gb2 = g0_sh[w + 4];
        float iv2 = gb2[u], fv2 = gb2[64 + u], gv2 = gb2[128 + u], ov2 = gb2[192 + u];
        cB = fv2 * cB + iv2 * gv2;
        hB = ov2 * tanh_fast(cB);
        h0_sh[w + 4][u] = hB;
      }
    } else {
      if (t >= 2) {                        // L1 update step t-2
        const float* gb = g1_sh[w];
        float iv = gb[u], fv = gb[64 + u], gv = gb[128 + u], ov = gb[192 + u];
        cA = fv * cA + iv * gv;
        hA = ov * tanh_fast(cA);
        h1_sh[w][u] = hA;
        const float* gb2 = g1_sh[w + 4];
        float iv2 = gb2[u], fv2 = gb2[64 + u], gv2 = gb2[128 + u], ov2 = gb2[192 + u];
        cB = fv2 * cB + iv2 * gv2;
        hB = ov2 * tanh_fast(cB);
        h1_sh[w + 4][u] = hB;
      }
    }
    __syncthreads();                       // h writes visible to next phase
  }

  // Final h1(11) -> hout from B threads' partitioned state. Coalesced.
  if (!isA) {
    hout[(seq0 + w) * Hd + u]     = hA;
    hout[(seq0 + w + 4) * Hd + u] = hB;
  }
}

// --------------------------------------------------------------------------
// Fused per-row node pipeline: wsum -> GCN r0 -> GCN r1 -> u/v precompute.
// One block per row (b,i); 256 threads. adj/ef rows staged into LDS with
// COALESCED loads; all weight reads coalesced via the k_prep transposes.
__global__ __launch_bounds__(256) void k_node(
    const float* __restrict__ ef,    const float* __restrict__ adj,
    const float* __restrict__ h0,
    const float* __restrict__ gcnWT, const float* __restrict__ gcn_b,
    const float* __restrict__ epWT,  const float* __restrict__ ep_b,
    const float* __restrict__ ln_g,  const float* __restrict__ ln_b,
    const float* __restrict__ W1aT,  const float* __restrict__ W1bT,
    const float* __restrict__ b1,
    float* __restrict__ uu, float* __restrict__ vt)
{
  __shared__ float ef_sh[Nd * Ed];   // 1000: edge_last row (coalesced stage)
  __shared__ float adj_sh[Nd];       // 200
  __shared__ float red[4][6];
  __shared__ float w6[6];
  __shared__ float hcur[Hd];

  const int row = blockIdx.x;      // b*200+i
  const int b = row / Nd, i = row % Nd;
  const int tid = threadIdx.x;

  const float* efrow = ef + (size_t)(((b * Wd + (Wd - 1)) * Nd + i)) * (Nd * Ed);
  for (int idx = tid; idx < Nd * Ed; idx += 256) ef_sh[idx] = efrow[idx];
  const float* adjrow = adj + (b * Nd + i) * Nd;
  if (tid < Nd) adj_sh[tid] = adjrow[tid];
  if (tid < Hd) hcur[tid] = h0[row * Hd + tid];
  __syncthreads();

  // ---- wsum: p[e] = sum_j adj*edge[e], p[5] = sum_j adj (order as before)
  float p[6] = {0.f, 0.f, 0.f, 0.f, 0.f, 0.f};
  if (tid < Nd) {
    float a = adj_sh[tid];
    p[5] = a;
    #pragma unroll
    for (int k = 0; k < Ed; ++k) p[k] = a * ef_sh[tid * Ed + k];
  }
  #pragma unroll
  for (int k = 0; k < 6; ++k) {
    float v = p[k];
    for (int off = 32; off > 0; off >>= 1) v += __shfl_down(v, off);
    p[k] = v;
  }
  if ((tid & 63) == 0) {
    #pragma unroll
    for (int k = 0; k < 6; ++k) red[tid >> 6][k] = p[k];
  }
  __syncthreads();
  if (tid < 6)
    w6[tid] = red[0][tid] + red[1][tid] + red[2][tid] + red[3][tid];
  __syncthreads();

  // ---- 2 GCN rounds (wave 0; coalesced transposed-weight reads)
  const int u = tid & 63;
  #pragma unroll
  for (int round = 0; round < 2; ++round) {
    float hnew = 0.f;
    if (tid < 64) {
      const float* gwT = gcnWT + round * 4096;   // [k][u]
      const float* ewT = epWT  + round * 320;    // [e][u]
      float acc = gcn_b[round * Hd + u] + w6[5] * ep_b[round * Hd + u];
      #pragma unroll
      for (int e = 0; e < Ed; ++e) acc += w6[e] * ewT[e * 64 + u];
      #pragma unroll 8
      for (int k = 0; k < Hd; ++k) acc += hcur[k] * gwT[k * 64 + u];

      float mu = acc;
      #pragma unroll
      for (int off = 1; off < 64; off <<= 1) mu += __shfl_xor(mu, off);
      mu *= (1.f / 64.f);
      float d = acc - mu;
      float var = d * d;
      #pragma unroll
      for (int off = 1; off < 64; off <<= 1) var += __shfl_xor(var, off);
      var *= (1.f / 64.f);
      float v = d * rsqrtf(var + LNEPS) * ln_g[round * Hd + u] + ln_b[round * Hd + u];
      hnew = fmaxf(v, 0.f);
    }
    __syncthreads();               // all reads of hcur done
    if (tid < 64) hcur[tid] = hnew;
    __syncthreads();
  }

  // ---- u/v precompute (threads 0..127; coalesced transposed W1 reads)
  if (tid < 64) {
    float acc = b1[tid];
    #pragma unroll 8
    for (int k = 0; k < Hd; ++k) acc += hcur[k] * W1aT[k * 64 + tid];
    uu[row * Hd + tid] = acc;
  } else if (tid < 128) {
    const int n = tid - 64;
    float acc = 0.f;
    #pragma unroll 8
    for (int k = 0; k < Hd; ++k) acc += hcur[k] * W1bT[k * 64 + n];
    vt[n * NSEQ + row] = acc;
  }
}

// --------------------------------------------------------------------------
// Edge MLP: thread per edge. z1[64] lives in VGPRs; W1c/W2/W3/b2 have
// wave-uniform indices -> scalar-pipe loads. uu/vt loads batched 16-at-a-
// time into temps (8 k per chunk; FP order identical) so 16 VMEM loads are
// outstanding instead of load->use serial.
__global__ __launch_bounds__(256) void k_mlp(
    const float* __restrict__ ef,
    const float* __restrict__ u, const float* __restrict__ vt,
    const float* __restrict__ W1,
    const float* __restrict__ W2, const float* __restrict__ b2,
    const float* __restrict__ W3, const float* __restrict__ b3,
    float* __restrict__ out)
{
  const int idx = blockIdx.x * 256 + threadIdx.x;   // < 320000
  const int b   = idx / (Nd * Nd);
  const int rem = idx - b * Nd * Nd;
  const int i   = rem / Nd;
  const int jj  = rem - i * Nd;

  const float* e = ef + (((b * Wd + (Wd - 1)) * Nd + i) * Nd + jj) * Ed;
  float e5[Ed];
  #pragma unroll
  for (int q = 0; q < Ed; ++q) e5[q] = e[q];

  const float* ur = u + (b * Nd + i) * Hd;
  const int vcol = b * Nd + jj;

  float z1[64];
  #pragma unroll
  for (int kb = 0; kb < 8; ++kb) {
    float uvv[8], vvv[8];                         // 16 loads issued together
    #pragma unroll
    for (int q = 0; q < 8; ++q) {
      uvv[q] = ur[kb * 8 + q];
      vvv[q] = vt[(kb * 8 + q) * NSEQ + vcol];
    }
    #pragma unroll
    for (int q = 0; q < 8; ++q) {
      int k = kb * 8 + q;
      float acc = uvv[q] + vvv[q];                // same order as ur[k]+vt[..]
      const float* w1c = W1 + k * 133 + 128;      // uniform -> scalar loads
      #pragma unroll
      for (int qq = 0; qq < Ed; ++qq) acc += e5[qq] * w1c[qq];
      z1[k] = fmaxf(acc, 0.f);
    }
  }

  float logit = b3[0];
  #pragma unroll 4
  for (int o = 0; o < 32; ++o) {
    float a0 = b2[o], a1 = 0.f, a2 = 0.f, a3 = 0.f;
    const float* w2 = W2 + o * 64;              // uniform -> scalar loads
    #pragma unroll
    for (int k = 0; k < 64; k += 4) {
      a0 += w2[k]     * z1[k];
      a1 += w2[k + 1] * z1[k + 1];
      a2 += w2[k + 2] * z1[k + 2];
      a3 += w2[k + 3] * z1[k + 3];
    }
    float z2 = fmaxf((a0 + a1) + (a2 + a3), 0.f);
    logit += W3[o] * z2;
  }
  out[idx] = 1.f / (1.f + __expf(-logit));
}

// --------------------------------------------------------------------------
extern "C" void kernel_launch(void* const* d_in, const int* in_sizes, int n_in,
                              void* d_out, int out_size, void* d_ws, size_t ws_size,
                              hipStream_t stream) {
  (void)in_sizes; (void)n_in; (void)out_size; (void)ws_size;
  const float* nf   = (const float*)d_in[0];
  const float* ef   = (const float*)d_in[1];
  const float* adj  = (const float*)d_in[2];
  const float* Wih0 = (const float*)d_in[3];
  const float* Whh0 = (const float*)d_in[4];
  const float* bih0 = (const float*)d_in[5];
  const float* bhh0 = (const float*)d_in[6];
  const float* Wih1 = (const float*)d_in[7];
  const float* Whh1 = (const float*)d_in[8];
  const float* bih1 = (const float*)d_in[9];
  const float* bhh1 = (const float*)d_in[10];
  const float* gcnW = (const float*)d_in[11];
  const float* gcnB = (const float*)d_in[12];
  const float* epW  = (const float*)d_in[13];
  const float* epB  = (const float*)d_in[14];
  const float* lnG  = (const float*)d_in[15];
  const float* lnB  = (const float*)d_in[16];
  const float* W1   = (const float*)d_in[17];
  const float* b1   = (const float*)d_in[18];
  const float* W2   = (const float*)d_in[19];
  const float* b2   = (const float*)d_in[20];
  const float* W3   = (const float*)d_in[21];
  const float* b3   = (const float*)d_in[22];
  float* out = (float*)d_out;

  // Workspace layout (floats).
  float* ws   = (float*)d_ws;
  float* h0   = ws;                        // 102,400
  float* uu   = h0   + 102400;             // 102,400
  float* vt   = uu   + 102400;             // 102,400
  float* gWT  = vt   + 102400;             // 8,192
  float* eWT  = gWT  + 8192;               // 640
  float* W1aT = eWT  + 640;                // 4,096
  float* W1bT = W1aT + 4096;               // 4,096

  k_prep      <<<67,        256, 0, stream>>>(gcnW, epW, W1, gWT, eWT, W1aT, W1bT);
  k_lstm_fused<<<NSEQ/SEQPB,512, 0, stream>>>(nf, Wih0, Whh0, bih0, bhh0,
                                              Wih1, Whh1, bih1, bhh1, h0);
  k_node      <<<1600,      256, 0, stream>>>(ef, adj, h0, gWT, gcnB, eWT, epB,
                                              lnG, lnB, W1aT, W1bT, b1, uu, vt);
  k_mlp       <<<1250,      256, 0, stream>>>(ef, uu, vt, W1, W2, b2, W3, b3, out);
}

// Round 10
// 260.112 us; speedup vs baseline: 1.0204x; 1.0204x over previous
//
#include <hip/hip_runtime.h>
#include <math.h>

// ---------------------------------------------------------------------------
// TemporalGCN: 2-layer LSTM (per-node sequences) -> 2 GCN rounds -> edge MLP.
//
// R18: consolidation round. R17 attributions: (1) lstm unroll 2->4 neutral
// (79.6 vs 80.2; overlap is REGISTER-starved: prefetching next seq's 16
// float4s needs 64 spare VGPRs, A-threads carry 128 wf) -- keep unroll 4;
// (2) k_mlp load-batching = -6.5us regression (2nd independent measurement,
// matches R11->R3 residual) -> reverted to the proven R9 scalar version,
// permanently. One new low-risk change: k_node k-loops unroll 8 -> 32.
// k_node is latency-bound on L2-resident weight streams (~200cyc L2): 8
// outstanding loads = ~25 cyc/elem; 32 amortizes to ~6. Single-acc chain
// order unchanged by unroll -> bit-exact. k_node VGPR ~40 -> +32 dests safe.
//
// Ledger: fills 143.5us (harness poison @80% HBM peak, uncontrollable) +
// lstm ~79.6 (DS-broadcast floor x structural serialization; occupancy/
// unroll/readlane/role-split all measured and exhausted) + node/mlp/prep
// ~36 -> this round targets the last bucket only.
//
// Bit-exactness: all accumulation chains verbatim -> absmax 0.0 preserved.
// ---------------------------------------------------------------------------

#define Hd   64
#define Ed   5
#define Fd   6
#define Bd   8
#define Wd   12
#define Nd   200
#define NSEQ (Bd*Nd)        // 1600 sequences (b,n)
#define NG   (4*Hd)         // 256 gate rows
#define SEQPB 8             // sequences per fused-LSTM block (200 % 8 == 0)
#define WP   (Wd + 1)       // padded t-columns in x_sh (col 12 = zeros)
#define LNEPS 1e-5f

__device__ __forceinline__ float sigm(float x) { return 1.0f / (1.0f + __expf(-x)); }
__device__ __forceinline__ float tanh_fast(float x) {
  float ax = fabsf(x);
  float t  = __expf(-2.0f * ax);
  float r  = (1.0f - t) / (1.0f + t);
  return copysignf(r, x);
}

// --------------------------------------------------------------------------
// Prep: gcnWT[round][k][u]; epWT[round][e][u]; W1aT[k][n]=W1[n][k];
// W1bT[k][n]=W1[n][64+k]. Sizes: 8192 + 640 + 4096 + 4096 = 17024 elements.
__global__ __launch_bounds__(256) void k_prep(
    const float* __restrict__ gcn_W, const float* __restrict__ ep_W,
    const float* __restrict__ W1,
    float* __restrict__ gcnWT, float* __restrict__ epWT,
    float* __restrict__ W1aT, float* __restrict__ W1bT)
{
  int idx = blockIdx.x * 256 + threadIdx.x;
  if (idx < 8192) {                        // gcnWT[r][k][u] = gcn_W[r][u][k]
    int round = idx >> 12, rem = idx & 4095;
    int k = rem >> 6, u = rem & 63;
    gcnWT[idx] = gcn_W[round * 4096 + u * 64 + k];
  } else if (idx < 8832) {                 // epWT[r][e][u] = ep_W[r][u][e]
    int r0 = idx - 8192;
    int round = r0 / 320, rem = r0 % 320;
    int e = rem >> 6, u = rem & 63;
    epWT[r0] = ep_W[round * 320 + u * Ed + e];
  } else if (idx < 12928) {                // W1aT[k][n] = W1[n][k]
    int r0 = idx - 8832;
    int k = r0 >> 6, n = r0 & 63;
    W1aT[r0] = W1[n * 133 + k];
  } else if (idx < 17024) {                // W1bT[k][n] = W1[n][64+k]
    int r0 = idx - 12928;
    int k = r0 >> 6, n = r0 & 63;
    W1bT[r0] = W1[n * 133 + 64 + k];
  }
}

// --------------------------------------------------------------------------
// Fused 2-layer LSTM (R17 verbatim; 79.6us, VGPR 116, no spill).
// 200 blocks x 512 threads, 8 seqs/block. Phase t in [0,13]:
//   A waves (tid<256): fused body for t<=12 -- L0 gate dot (stored iff
//     t<12) + xproj off the SAME h0_sh b128 stream (stored iff t>=1).
//   B waves: L1 gates step t-2 (t>=2), a0 seeded from x1_sh[(t-1)&1].
// barrier; L0 update (A, t<12), L1 update (B, t>=2); barrier.
__global__ __launch_bounds__(512) void k_lstm_fused(
    const float* __restrict__ nf,                       // (B,W,N,F)
    const float* __restrict__ Wih0, const float* __restrict__ Whh0,
    const float* __restrict__ bih0, const float* __restrict__ bhh0,
    const float* __restrict__ Wih1, const float* __restrict__ Whh1,
    const float* __restrict__ bih1, const float* __restrict__ bhh1,
    float* __restrict__ hout)                           // (NSEQ, H)
{
  __shared__ float x_sh[SEQPB][WP * Fd];   // 624 (col 12 zeroed)
  __shared__ float wx_sh[NG * Fd];         // 1536: Wih0 rows (row-major)
  __shared__ float h0_sh[SEQPB][Hd];       // 512
  __shared__ float h1_sh[SEQPB][Hd];       // 512
  __shared__ float g0_sh[SEQPB][NG];       // 2048 (post-activation gates L0)
  __shared__ float g1_sh[SEQPB][NG];       // 2048 (post-activation gates L1)
  __shared__ float x1_sh[2][SEQPB][NG];    // 4096 (xv = Wih1.h0 + bias1)

  const int tid  = threadIdx.x;
  const int seq0 = blockIdx.x * SEQPB;
  const int b    = seq0 / Nd;              // uniform (200 % 8 == 0)
  const int n0   = seq0 % Nd;

  for (int idx = tid; idx < SEQPB * WP * Fd; idx += 512) {
    int s = idx / (WP * Fd), r = idx - s * (WP * Fd);
    int t = r / Fd, f = r - t * Fd;
    x_sh[s][r] = (t < Wd) ? nf[((b * Wd + t) * Nd + (n0 + s)) * Fd + f] : 0.f;
  }
  for (int idx = tid; idx < NG * Fd; idx += 512)
    wx_sh[idx] = Wih0[idx];                // linear copy (row-major match)
  ((float*)h0_sh)[tid] = 0.f;              // 512 floats, one per thread
  ((float*)h1_sh)[tid] = 0.f;

  const bool isA = (tid < 256);
  const int j  = tid & 255;                // gate row within this layer
  const int jt = j >> 6;                   // 0=i,1=f,2=g,3=o (wave-uniform)
  const int u  = tid & 63;
  const int w  = (tid >> 6) & 3;           // update ownership: seqs {w, w+4}

  // Per-thread weights: A = Whh0[j] + Wih1[j] (128 wf; Wih0 row via LDS);
  // B = Whh1[j] (64 wf). Plain launch_bounds -> AGPR-backed overflow OK.
  float4 wh[16];                           // Whh0 row j (A) / Whh1 row j (B)
  float4 wi1[16];                          // Wih1 row j (A only)
  float  bias0 = 0.f, bias1 = 0.f;
  if (isA) {
    const float4* wr = (const float4*)(Whh0 + j * Hd);
    #pragma unroll
    for (int q = 0; q < 16; ++q) wh[q] = wr[q];
    const float4* xr = (const float4*)(Wih1 + j * Hd);
    #pragma unroll
    for (int q = 0; q < 16; ++q) wi1[q] = xr[q];
    bias0 = bih0[j] + bhh0[j];
    bias1 = bih1[j] + bhh1[j];
  } else {
    const float4* wr = (const float4*)(Whh1 + j * Hd);
    #pragma unroll
    for (int q = 0; q < 16; ++q) wh[q] = wr[q];
  }

  float cA = 0.f, cB = 0.f;                // cell states for seqs w, w+4
  float hA = 0.f, hB = 0.f;                // B threads: final h1 for w, w+4
  const float* wxp = wx_sh + j * Fd;       // A's Wih0 row (LDS, 2-way = free)
  __syncthreads();

  for (int t = 0; t <= Wd + 1; ++t) {
    // ================= gate section ======================================
    if (isA) {
      if (t <= Wd) {                       // single fused body for t in [0,12]
        #pragma unroll 4
        for (int s = 0; s < SEQPB; ++s) {
          const float* xp = &x_sh[s][t * Fd];        // col 12 = zeros
          float a0 = bias0, a1 = 0.f, a2 = 0.f, a3 = 0.f;
          #pragma unroll
          for (int f = 0; f < Fd; ++f) a1 += xp[f] * wxp[f];
          float xacc = 0.f;
          const float4* h4 = (const float4*)h0_sh[s];
          #pragma unroll
          for (int q = 0; q < 16; ++q) {
            float4 hv = h4[q];                       // ONE b128, two dots
            float d = hv.x * wh[q].x + hv.y * wh[q].y + hv.z * wh[q].z + hv.w * wh[q].w;
            if ((q & 3) == 0) a0 += d; else if ((q & 3) == 1) a1 += d;
            else if ((q & 3) == 2) a2 += d; else a3 += d;
            xacc = fmaf(hv.x, wi1[q].x, xacc);       // xproj for L1 step t-1
            xacc = fmaf(hv.y, wi1[q].y, xacc);
            xacc = fmaf(hv.z, wi1[q].z, xacc);
            xacc = fmaf(hv.w, wi1[q].w, xacc);
          }
          float acc = (a0 + a1) + (a2 + a3);
          if (t < Wd)  g0_sh[s][j] = (jt == 2) ? tanh_fast(acc) : sigm(acc);
          if (t >= 1)  x1_sh[t & 1][s][j] = xacc + bias1;
        }
      }
    } else {
      if (t >= 2) {                        // L1 gates step t-2
        #pragma unroll 4
        for (int s = 0; s < SEQPB; ++s) {
          float a0 = x1_sh[(t - 1) & 1][s][j];   // xv(t-2), written phase t-1
          float a1 = 0.f, a2 = 0.f, a3 = 0.f;
          const float4* h4 = (const float4*)h1_sh[s];
          #pragma unroll
          for (int q = 0; q < 16; ++q) {
            float4 hv = h4[q];
            float d = hv.x * wh[q].x + hv.y * wh[q].y + hv.z * wh[q].z + hv.w * wh[q].w;
            if ((q & 3) == 0) a0 += d; else if ((q & 3) == 1) a1 += d;
            else if ((q & 3) == 2) a2 += d; else a3 += d;
          }
          float acc = (a0 + a1) + (a2 + a3);
          g1_sh[s][j] = (jt == 2) ? tanh_fast(acc) : sigm(acc);
        }
      }
    }
    __syncthreads();                       // gates/xv ready; all h reads done

    // ================= update section (verbatim R9 ownership) ============
    if (isA) {
      if (t < Wd) {                        // L0 update step t
        const float* gb = g0_sh[w];
        float iv = gb[u], fv = gb[64 + u], gv = gb[128 + u], ov = gb[192 + u];
        cA = fv * cA + iv * gv;
        hA = ov * tanh_fast(cA);
        h0_sh[w][u] = hA;
        const float* gb2 = g0_sh[w + 4];
        float iv2 = gb2[u], fv2 = gb2[64 + u], gv2 = gb2[128 + u], ov2 = gb2[192 + u];
        cB = fv2 * cB + iv2 * gv2;
        hB = ov2 * tanh_fast(cB);
        h0_sh[w + 4][u] = hB;
      }
    } else {
      if (t >= 2) {                        // L1 update step t-2
        const float* gb = g1_sh[w];
        float iv = gb[u], fv = gb[64 + u], gv = gb[128 + u], ov = gb[192 + u];
        cA = fv * cA + iv * gv;
        hA = ov * tanh_fast(cA);
        h1_sh[w][u] = hA;
        const float* gb2 = g1_sh[w + 4];
        float iv2 = gb2[u], fv2 = gb2[64 + u], gv2 = gb2[128 + u], ov2 = gb2[192 + u];
        cB = fv2 * cB + iv2 * gv2;
        hB = ov2 * tanh_fast(cB);
        h1_sh[w + 4][u] = hB;
      }
    }
    __syncthreads();                       // h writes visible to next phase
  }

  // Final h1(11) -> hout from B threads' partitioned state. Coalesced.
  if (!isA) {
    hout[(seq0 + w) * Hd + u]     = hA;
    hout[(seq0 + w + 4) * Hd + u] = hB;
  }
}

// --------------------------------------------------------------------------
// Fused per-row node pipeline: wsum -> GCN r0 -> GCN r1 -> u/v precompute.
// One block per row (b,i); 256 threads. R18: the three 64-k loops unroll
// 8 -> 32 (latency-bound on L2-resident weight streams; 32 outstanding
// loads amortize ~200cyc L2 latency to ~6 cyc/elem). Acc chain unchanged.
__global__ __launch_bounds__(256) void k_node(
    const float* __restrict__ ef,    const float* __restrict__ adj,
    const float* __restrict__ h0,
    const float* __restrict__ gcnWT, const float* __restrict__ gcn_b,
    const float* __restrict__ epWT,  const float* __restrict__ ep_b,
    const float* __restrict__ ln_g,  const float* __restrict__ ln_b,
    const float* __restrict__ W1aT,  const float* __restrict__ W1bT,
    const float* __restrict__ b1,
    float* __restrict__ uu, float* __restrict__ vt)
{
  __shared__ float ef_sh[Nd * Ed];   // 1000: edge_last row (coalesced stage)
  __shared__ float adj_sh[Nd];       // 200
  __shared__ float red[4][6];
  __shared__ float w6[6];
  __shared__ float hcur[Hd];

  const int row = blockIdx.x;      // b*200+i
  const int b = row / Nd, i = row % Nd;
  const int tid = threadIdx.x;

  const float* efrow = ef + (size_t)(((b * Wd + (Wd - 1)) * Nd + i)) * (Nd * Ed);
  for (int idx = tid; idx < Nd * Ed; idx += 256) ef_sh[idx] = efrow[idx];
  const float* adjrow = adj + (b * Nd + i) * Nd;
  if (tid < Nd) adj_sh[tid] = adjrow[tid];
  if (tid < Hd) hcur[tid] = h0[row * Hd + tid];
  __syncthreads();

  // ---- wsum: p[e] = sum_j adj*edge[e], p[5] = sum_j adj (order as before)
  float p[6] = {0.f, 0.f, 0.f, 0.f, 0.f, 0.f};
  if (tid < Nd) {
    float a = adj_sh[tid];
    p[5] = a;
    #pragma unroll
    for (int k = 0; k < Ed; ++k) p[k] = a * ef_sh[tid * Ed + k];
  }
  #pragma unroll
  for (int k = 0; k < 6; ++k) {
    float v = p[k];
    for (int off = 32; off > 0; off >>= 1) v += __shfl_down(v, off);
    p[k] = v;
  }
  if ((tid & 63) == 0) {
    #pragma unroll
    for (int k = 0; k < 6; ++k) red[tid >> 6][k] = p[k];
  }
  __syncthreads();
  if (tid < 6)
    w6[tid] = red[0][tid] + red[1][tid] + red[2][tid] + red[3][tid];
  __syncthreads();

  // ---- 2 GCN rounds (wave 0; coalesced transposed-weight reads)
  const int u = tid & 63;
  #pragma unroll
  for (int round = 0; round < 2; ++round) {
    float hnew = 0.f;
    if (tid < 64) {
      const float* gwT = gcnWT + round * 4096;   // [k][u]
      const float* ewT = epWT  + round * 320;    // [e][u]
      float acc = gcn_b[round * Hd + u] + w6[5] * ep_b[round * Hd + u];
      #pragma unroll
      for (int e = 0; e < Ed; ++e) acc += w6[e] * ewT[e * 64 + u];
      #pragma unroll 32
      for (int k = 0; k < Hd; ++k) acc += hcur[k] * gwT[k * 64 + u];

      float mu = acc;
      #pragma unroll
      for (int off = 1; off < 64; off <<= 1) mu += __shfl_xor(mu, off);
      mu *= (1.f / 64.f);
      float d = acc - mu;
      float var = d * d;
      #pragma unroll
      for (int off = 1; off < 64; off <<= 1) var += __shfl_xor(var, off);
      var *= (1.f / 64.f);
      float v = d * rsqrtf(var + LNEPS) * ln_g[round * Hd + u] + ln_b[round * Hd + u];
      hnew = fmaxf(v, 0.f);
    }
    __syncthreads();               // all reads of hcur done
    if (tid < 64) hcur[tid] = hnew;
    __syncthreads();
  }

  // ---- u/v precompute (threads 0..127; coalesced transposed W1 reads)
  if (tid < 64) {
    float acc = b1[tid];
    #pragma unroll 32
    for (int k = 0; k < Hd; ++k) acc += hcur[k] * W1aT[k * 64 + tid];
    uu[row * Hd + tid] = acc;
  } else if (tid < 128) {
    const int n = tid - 64;
    float acc = 0.f;
    #pragma unroll 32
    for (int k = 0; k < Hd; ++k) acc += hcur[k] * W1bT[k * 64 + n];
    vt[n * NSEQ + row] = acc;
  }
}

// --------------------------------------------------------------------------
// Edge MLP: thread per edge. z1[64] lives in VGPRs; W1c/W2/W3/b2 have
// wave-uniform indices -> scalar-pipe loads, fmac v,s,v at VALU issue peak.
// (Proven R9/R16 version; load-batching measured -6.5us twice -> reverted.)
__global__ __launch_bounds__(256) void k_mlp(
    const float* __restrict__ ef,
    const float* __restrict__ u, const float* __restrict__ vt,
    const float* __restrict__ W1,
    const float* __restrict__ W2, const float* __restrict__ b2,
    const float* __restrict__ W3, const float* __restrict__ b3,
    float* __restrict__ out)
{
  const int idx = blockIdx.x * 256 + threadIdx.x;   // < 320000
  const int b   = idx / (Nd * Nd);
  const int rem = idx - b * Nd * Nd;
  const int i   = rem / Nd;
  const int jj  = rem - i * Nd;

  const float* e = ef + (((b * Wd + (Wd - 1)) * Nd + i) * Nd + jj) * Ed;
  float e5[Ed];
  #pragma unroll
  for (int q = 0; q < Ed; ++q) e5[q] = e[q];

  const float* ur = u + (b * Nd + i) * Hd;
  const int vcol = b * Nd + jj;

  float z1[64];
  #pragma unroll
  for (int k = 0; k < 64; ++k) {
    float acc = ur[k] + vt[k * NSEQ + vcol];
    const float* w1c = W1 + k * 133 + 128;      // uniform -> scalar loads
    #pragma unroll
    for (int q = 0; q < Ed; ++q) acc += e5[q] * w1c[q];
    z1[k] = fmaxf(acc, 0.f);
  }

  float logit = b3[0];
  #pragma unroll 4
  for (int o = 0; o < 32; ++o) {
    float a0 = b2[o], a1 = 0.f, a2 = 0.f, a3 = 0.f;
    const float* w2 = W2 + o * 64;              // uniform -> scalar loads
    #pragma unroll
    for (int k = 0; k < 64; k += 4) {
      a0 += w2[k]     * z1[k];
      a1 += w2[k + 1] * z1[k + 1];
      a2 += w2[k + 2] * z1[k + 2];
      a3 += w2[k + 3] * z1[k + 3];
    }
    float z2 = fmaxf((a0 + a1) + (a2 + a3), 0.f);
    logit += W3[o] * z2;
  }
  out[idx] = 1.f / (1.f + __expf(-logit));
}

// --------------------------------------------------------------------------
extern "C" void kernel_launch(void* const* d_in, const int* in_sizes, int n_in,
                              void* d_out, int out_size, void* d_ws, size_t ws_size,
                              hipStream_t stream) {
  (void)in_sizes; (void)n_in; (void)out_size; (void)ws_size;
  const float* nf   = (const float*)d_in[0];
  const float* ef   = (const float*)d_in[1];
  const float* adj  = (const float*)d_in[2];
  const float* Wih0 = (const float*)d_in[3];
  const float* Whh0 = (const float*)d_in[4];
  const float* bih0 = (const float*)d_in[5];
  const float* bhh0 = (const float*)d_in[6];
  const float* Wih1 = (const float*)d_in[7];
  const float* Whh1 = (const float*)d_in[8];
  const float* bih1 = (const float*)d_in[9];
  const float* bhh1 = (const float*)d_in[10];
  const float* gcnW = (const float*)d_in[11];
  const float* gcnB = (const float*)d_in[12];
  const float* epW  = (const float*)d_in[13];
  const float* epB  = (const float*)d_in[14];
  const float* lnG  = (const float*)d_in[15];
  const float* lnB  = (const float*)d_in[16];
  const float* W1   = (const float*)d_in[17];
  const float* b1   = (const float*)d_in[18];
  const float* W2   = (const float*)d_in[19];
  const float* b2   = (const float*)d_in[20];
  const float* W3   = (const float*)d_in[21];
  const float* b3   = (const float*)d_in[22];
  float* out = (float*)d_out;

  // Workspace layout (floats).
  float* ws   = (float*)d_ws;
  float* h0   = ws;                        // 102,400
  float* uu   = h0   + 102400;             // 102,400
  float* vt   = uu   + 102400;             // 102,400
  float* gWT  = vt   + 102400;             // 8,192
  float* eWT  = gWT  + 8192;               // 640
  float* W1aT = eWT  + 640;                // 4,096
  float* W1bT = W1aT + 4096;               // 4,096

  k_prep      <<<67,        256, 0, stream>>>(gcnW, epW, W1, gWT, eWT, W1aT, W1bT);
  k_lstm_fused<<<NSEQ/SEQPB,512, 0, stream>>>(nf, Wih0, Whh0, bih0, bhh0,
                                              Wih1, Whh1, bih1, bhh1, h0);
  k_node      <<<1600,      256, 0, stream>>>(ef, adj, h0, gWT, gcnB, eWT, epB,
                                              lnG, lnB, W1aT, W1bT, b1, uu, vt);
  k_mlp       <<<1250,      256, 0, stream>>>(ef, uu, vt, W1, W2, b2, W3, b3, out);
}